// Round 9
// baseline (286.145 us; speedup 1.0000x reference)
//
#include <hip/hip_runtime.h>

#define HW 32768      // H*W per batch = 128*256
#define WIDTH 256

typedef float f32x4 __attribute__((ext_vector_type(4)));
typedef short s16x8 __attribute__((ext_vector_type(8)));

__device__ __forceinline__ unsigned short f2bf(float f){
    unsigned int u = __float_as_uint(f);
    u += 0x7FFFu + ((u >> 16) & 1u);      // round-to-nearest-even
    return (unsigned short)(u >> 16);
}
__device__ __forceinline__ unsigned int pk2(float a, float b){
    return (unsigned int)f2bf(a) | ((unsigned int)f2bf(b) << 16);
}

// ---------------------------------------------------------------------------
// k_pre: blocks 0..63 = W1/W2 pre-pack into bf16 MFMA A-fragment layout
//        block 64 = collapsed geo path (M = Wsel x Wgeo, c0 = collapsed bias)
// ---------------------------------------------------------------------------
__global__ void k_pre(const float* __restrict__ W1, const float* __restrict__ W2,
                      unsigned int* __restrict__ Wb,
                      const float* __restrict__ Wsel, const float* __restrict__ bsel,
                      const float* __restrict__ Wgeo, const float* __restrict__ bgeo,
                      float* __restrict__ M, float* __restrict__ c0)
{
    if (blockIdx.x < 64){
        const int pi = blockIdx.x * 256 + threadIdx.x;   // 0..16383
        const int j2   = pi & 3;
        const int l15  = (pi >> 2) & 15;
        const int quad = (pi >> 6) & 3;
        const int m    = (pi >> 8) & 7;
        const int kk   = (pi >> 11) & 3;
        const int F    = (pi >> 13) & 1;
        const float* Wm = F ? W2 : W1;
        const int row = m * 16 + l15;
        const int ch  = kk * 32 + quad * 8 + j2 * 2;
        Wb[pi] = pk2(Wm[row * 128 + ch], Wm[row * 128 + ch + 1]);
    } else {
        for (int u = threadIdx.x; u < 444; u += 256){
            if (u < 441){
                int s = u / 147; int r = u % 147; int i = r / 49; int k = r % 49;
                float acc = 0.f;
                for (int o = 0; o < 96; ++o)
                    acc += Wsel[s * 288 + i * 96 + o] * Wgeo[o * 49 + k];
                M[u] = acc;
            } else {
                int s = u - 441;
                float acc = bsel[s];
                for (int i = 0; i < 3; ++i)
                    for (int o = 0; o < 96; ++o)
                        acc += Wsel[s * 288 + i * 96 + o] * bgeo[o];
                c0[s] = acc;
            }
        }
    }
}

// ---------------------------------------------------------------------------
// Fused kernel, 256 threads (4 waves), one (b,h) row per block.
// This round: break phase lockstep — the epilogue's logit pass (150 KB of cv
// loads, dependency-free) is hoisted INTO the correlation phase (pure
// LDS+MFMA, no global traffic) in 4/3/3/3 dd-chunks between st iterations,
// keeping the memory pipe busy while the matrix pipe works.
// f2s stride reverted to 132 shorts (66 words = 2 mod 32: free 2-way banks;
// the 144 variant measured WORSE conflicts, 1.19M -> 1.82M).
// ---------------------------------------------------------------------------
__global__ __launch_bounds__(256, 2) void k_fused(
    const float* __restrict__ fl, const float* __restrict__ fr,
    const unsigned int* __restrict__ Wbu,
    const float* __restrict__ b1, const float* __restrict__ b2,
    const float* __restrict__ cv0, const float* __restrict__ cv1,
    const float* __restrict__ cv2,
    const float* __restrict__ Mg, const float* __restrict__ c0g,
    float* __restrict__ icO, float* __restrict__ finalO, float* __restrict__ wO)
{
    __shared__ __align__(16) char pool[67584];      // f2s[256][132] bf16 -> G[256][66] f32
    __shared__ float s1[256], s2[256];
    __shared__ float Ms[441];
    __shared__ float c0s[3];
    unsigned short* f2s = (unsigned short*)pool;    // [256 px][132] bf16
    float* G            = (float*)pool;             // [256 rows][66] f32

    const int blk  = blockIdx.x;          // 512 = 4 b x 128 h
    const int b    = blk >> 7;
    const int h    = blk & 127;
    const int tid  = threadIdx.x;
    const int wv   = tid >> 6;            // 0..3
    const int lane = tid & 63;
    const int quad = lane >> 4;
    const int l15  = lane & 15;

    for (int i = tid; i < 441; i += 256) Ms[i] = Mg[i];
    if (tid < 3) c0s[tid] = c0g[tid];

    const float* feats[2] = { fl + (size_t)b * 128 * HW + h * WIDTH,
                              fr + (size_t)b * 128 * HW + h * WIDTH };
    const float* bss[2]   = { b1, b2 };

    unsigned int f1p[64];                 // f1 raw bf16 pairs (wave's 64 px)

    #pragma unroll 1
    for (int Fi = 0; Fi < 2; ++Fi){
        const int F = 1 - Fi;             // f2 first, then f1
        const float* featB = feats[F];
        const float* bias  = bss[F];
        const unsigned int* WbF = Wbu + F * 8192;

        f32x4 acc[8][4];
        #pragma unroll
        for (int m = 0; m < 8; ++m)
            #pragma unroll
            for (int nt = 0; nt < 4; ++nt)
                acc[m][nt] = (f32x4){0.f, 0.f, 0.f, 0.f};

        float buf[4][8];
        // tile t = kk*4+nt ; px = wv*64 + nt*16 + l15 ; preload t = 0,1,2
        #pragma unroll
        for (int t = 0; t < 3; ++t){
            const float* bp = featB + (size_t)(quad * 8) * HW + wv * 64 + t * 16 + l15;
            #pragma unroll
            for (int j = 0; j < 8; ++j) buf[t][j] = bp[(size_t)j * HW];
        }

        #pragma unroll
        for (int kk = 0; kk < 4; ++kk){
            // A-frags: one 16-B coalesced load per m (pre-packed bf16, L2-hot)
            s16x8 af[8];
            #pragma unroll
            for (int m = 0; m < 8; ++m)
                af[m] = *(const s16x8*)&WbF[(((kk * 8 + m) * 4 + quad) * 16 + l15) * 4];

            #pragma unroll
            for (int nt = 0; nt < 4; ++nt){
                const int t = kk * 4 + nt;
                if (t + 3 < 16){          // 3-deep pipeline
                    const int kk2 = (t + 3) >> 2, nt2 = (t + 3) & 3;
                    const float* bp = featB + (size_t)(kk2 * 32 + quad * 8) * HW
                                      + wv * 64 + nt2 * 16 + l15;
                    #pragma unroll
                    for (int j = 0; j < 8; ++j) buf[(t + 3) & 3][j] = bp[(size_t)j * HW];
                }
                const float* cur = buf[t & 3];
                union { unsigned int u[4]; s16x8 v; } rb;
                rb.u[0] = pk2(cur[0], cur[1]); rb.u[1] = pk2(cur[2], cur[3]);
                rb.u[2] = pk2(cur[4], cur[5]); rb.u[3] = pk2(cur[6], cur[7]);
                #pragma unroll
                for (int m = 0; m < 8; ++m)
                    acc[m][nt] = __builtin_amdgcn_mfma_f32_16x16x32_bf16(af[m], rb.v, acc[m][nt], 0, 0, 0);
            }
        }

        // bias + inverse-norm per pixel
        float inv[4];
        #pragma unroll
        for (int nt = 0; nt < 4; ++nt){
            #pragma unroll
            for (int m = 0; m < 8; ++m)
                acc[m][nt] += *(const f32x4*)(bias + m * 16 + quad * 4);
            float n2 = 0.f;
            #pragma unroll
            for (int m = 0; m < 8; ++m)
                #pragma unroll
                for (int r = 0; r < 4; ++r)
                    n2 += acc[m][nt][r] * acc[m][nt][r];
            n2 += __shfl_xor(n2, 16, 64);
            n2 += __shfl_xor(n2, 32, 64);
            inv[nt] = 1.f / (sqrtf(n2) + 1e-8f);
        }

        if (F == 1){                      // f2 -> LDS (raw bf16) + s2
            if (quad == 0){
                #pragma unroll
                for (int nt = 0; nt < 4; ++nt) s2[wv * 64 + nt * 16 + l15] = inv[nt];
            }
            #pragma unroll
            for (int nt = 0; nt < 4; ++nt){
                const int px = wv * 64 + nt * 16 + l15;
                #pragma unroll
                for (int m = 0; m < 8; ++m){
                    uint2 p;
                    p.x = pk2(acc[m][nt][0], acc[m][nt][1]);
                    p.y = pk2(acc[m][nt][2], acc[m][nt][3]);
                    *(uint2*)&f2s[px * 132 + m * 16 + quad * 4] = p;
                }
            }
        } else {                          // f1 -> registers (raw bf16) + s1
            #pragma unroll
            for (int m = 0; m < 8; ++m)
                #pragma unroll
                for (int nt = 0; nt < 4; ++nt){
                    f1p[m * 8 + nt * 2 + 0] = pk2(acc[m][nt][0], acc[m][nt][1]);
                    f1p[m * 8 + nt * 2 + 1] = pk2(acc[m][nt][2], acc[m][nt][3]);
                }
            if (quad == 0){
                #pragma unroll
                for (int nt = 0; nt < 4; ++nt) s1[wv * 64 + nt * 16 + l15] = inv[nt];
            }
        }
    }
    __syncthreads();                      // f2s (and Ms) complete

    // ---- epilogue mapping (needed now: logit pass is hoisted into corr) ----
    const int g   = tid >> 2;             // 0..63 -> px0 = 4g
    const int sl  = tid & 3;              // dd slice: sl*13 .. sl*13+12 (sl 3: 10)
    const int px0 = g * 4;
    const size_t rowoff = (size_t)h * WIDTH + px0;
    const size_t cvbase = (size_t)b * 49 * HW + rowoff;
    float* icb = icO    + cvbase;
    float* fnb = finalO + cvbase;
    const float* c0p = cv0 + cvbase;
    const float* c1p = cv1 + cvbase;
    const float* c2p = cv2 + cvbase;

    f32x4 lg0 = (f32x4){0.f,0.f,0.f,0.f};
    f32x4 lg1 = (f32x4){0.f,0.f,0.f,0.f};
    f32x4 lg2 = (f32x4){0.f,0.f,0.f,0.f};

    // ---- correlation with interleaved cv logit-pass (4/3/3/3 dd chunks) ----
    f32x4 acc_c[4][4];
    #pragma unroll
    for (int st = 0; st < 4; ++st)
        #pragma unroll
        for (int ct = 0; ct < 4; ++ct)
            acc_c[st][ct] = (f32x4){0.f, 0.f, 0.f, 0.f};

    const int ibeg[4] = {0, 4, 7, 10};
    const int icnt[4] = {4, 3, 3, 3};

    #pragma unroll
    for (int st = 0; st < 4; ++st){
        // issue this chunk's cv loads (in flight under the MFMAs below)
        f32x4 la0[4], la1[4], la2[4];
        #pragma unroll
        for (int c = 0; c < 4; ++c){
            if (c < icnt[st]){
                const int dd = sl * 13 + ibeg[st] + c;
                if (dd < 49){
                    la0[c] = *(const f32x4*)(c0p + (size_t)dd * HW);
                    la1[c] = *(const f32x4*)(c1p + (size_t)dd * HW);
                    la2[c] = *(const f32x4*)(c2p + (size_t)dd * HW);
                }
            }
        }

        s16x8 afc[4];
        #pragma unroll
        for (int kk = 0; kk < 4; ++kk){
            union { unsigned int u[4]; s16x8 v; } r;
            #pragma unroll
            for (int j2 = 0; j2 < 4; ++j2){
                const int rp  = j2 & 1;
                const int qs  = (quad & 1) * 2 + (j2 >> 1);
                const int src = qs * 16 + l15;
                unsigned int a0 = (unsigned int)__shfl((int)f1p[(kk * 2 + 0) * 8 + st * 2 + rp], src, 64);
                unsigned int a1 = (unsigned int)__shfl((int)f1p[(kk * 2 + 1) * 8 + st * 2 + rp], src, 64);
                r.u[j2] = (quad >> 1) ? a1 : a0;
            }
            afc[kk] = r.v;
        }
        #pragma unroll
        for (int ct = 0; ct < 4; ++ct){
            const int s = wv * 64 + st * 16 + ct * 16 + l15 - 24;
            const bool valid = (s >= 0) && (s < WIDTH);
            const int sc = valid ? s : 0;
            #pragma unroll
            for (int kk = 0; kk < 4; ++kk){
                union { uint2 q2[2]; s16x8 v; } rb;
                rb.q2[0] = *(const uint2*)&f2s[sc * 132 + kk * 32 + quad * 8];
                rb.q2[1] = *(const uint2*)&f2s[sc * 132 + kk * 32 + quad * 8 + 4];
                s16x8 bf = rb.v;
                if (!valid) bf = (s16x8){0,0,0,0,0,0,0,0};
                acc_c[st][ct] = __builtin_amdgcn_mfma_f32_16x16x32_bf16(afc[kk], bf, acc_c[st][ct], 0, 0, 0);
            }
        }

        // consume the chunk into logit partials
        #pragma unroll
        for (int c = 0; c < 4; ++c){
            if (c < icnt[st]){
                const int dd = sl * 13 + ibeg[st] + c;
                if (dd < 49){
                    const float m00 = Ms[dd],       m01 = Ms[49  + dd], m02 = Ms[98  + dd];
                    const float m10 = Ms[147 + dd], m11 = Ms[196 + dd], m12 = Ms[245 + dd];
                    const float m20 = Ms[294 + dd], m21 = Ms[343 + dd], m22 = Ms[392 + dd];
                    #pragma unroll
                    for (int p = 0; p < 4; ++p){
                        lg0[p] += m00 * la0[c][p] + m01 * la1[c][p] + m02 * la2[c][p];
                        lg1[p] += m10 * la0[c][p] + m11 * la1[c][p] + m12 * la2[c][p];
                        lg2[p] += m20 * la0[c][p] + m21 * la1[c][p] + m22 * la2[c][p];
                    }
                }
            }
        }
    }
    __syncthreads();                      // all f2s reads done; G overwrites pool
    #pragma unroll
    for (int st = 0; st < 4; ++st)
        #pragma unroll
        for (int ct = 0; ct < 4; ++ct)
            #pragma unroll
            for (int r = 0; r < 4; ++r)
                G[((wv * 4 + st) * 16 + quad * 4 + r) * 66 + ct * 16 + l15] = acc_c[st][ct][r];
    __syncthreads();

    // reduce logit partials across the 4 slices (lanes tid^1, tid^2: same wave)
    #pragma unroll
    for (int p = 0; p < 4; ++p){
        lg0[p] += __shfl_xor(lg0[p], 1, 64); lg0[p] += __shfl_xor(lg0[p], 2, 64);
        lg1[p] += __shfl_xor(lg1[p], 1, 64); lg1[p] += __shfl_xor(lg1[p], 2, 64);
        lg2[p] += __shfl_xor(lg2[p], 1, 64); lg2[p] += __shfl_xor(lg2[p], 2, 64);
    }

    // softmax per pixel (each thread: its 4 px; redundant across slices)
    f32x4 w0v, w1v, w2v;
    #pragma unroll
    for (int p = 0; p < 4; ++p){
        const float L0 = c0s[0] + lg0[p];
        const float L1 = c0s[1] + lg1[p];
        const float L2 = c0s[2] + lg2[p];
        const float mx = fmaxf(L0, fmaxf(L1, L2));
        const float e0 = expf(L0 - mx), e1 = expf(L1 - mx), e2 = expf(L2 - mx);
        const float einv = 1.f / (e0 + e1 + e2);
        w0v[p] = e0 * einv; w1v[p] = e1 * einv; w2v[p] = e2 * einv;
    }
    if (sl == 0){
        float* wb = wO + (size_t)b * 3 * HW + rowoff;
        *(f32x4*)(wb)          = w0v;
        *(f32x4*)(wb + HW)     = w1v;
        *(f32x4*)(wb + 2 * HW) = w2v;
    }

    const f32x4 s1v = *(const f32x4*)&s1[px0];

    // pass 2: re-read cv (L2-hot), icv from LDS G, write ic + final (float4)
    #pragma unroll
    for (int i = 0; i < 13; ++i){
        const int dd = sl * 13 + i;
        if (dd < 49){
            const f32x4 a0 = *(const f32x4*)(c0p + (size_t)dd * HW);
            const f32x4 a1 = *(const f32x4*)(c1p + (size_t)dd * HW);
            const f32x4 a2 = *(const f32x4*)(c2p + (size_t)dd * HW);
            f32x4 icv, fv;
            #pragma unroll
            for (int p = 0; p < 4; ++p){
                const int px = px0 + p;
                int s2i = px + 24 - dd;
                s2i = s2i < 0 ? 0 : (s2i > 255 ? 255 : s2i);   // OOB -> G entry is 0 anyway
                icv[p] = G[px * 66 + (px & 15) + 48 - dd] * s1v[p] * s2[s2i];
                fv[p]  = icv[p] + w0v[p] * a0[p] + w1v[p] * a1[p] + w2v[p] * a2[p];
            }
            *(f32x4*)(icb + (size_t)dd * HW) = icv;
            *(f32x4*)(fnb + (size_t)dd * HW) = fv;
        }
    }
}

// ---------------------------------------------------------------------------
extern "C" void kernel_launch(void* const* d_in, const int* in_sizes, int n_in,
                              void* d_out, int out_size, void* d_ws, size_t ws_size,
                              hipStream_t stream)
{
    const float* feat_l1 = (const float*)d_in[0];
    const float* feat_r1 = (const float*)d_in[1];
    const float* cv0     = (const float*)d_in[2];
    const float* cv1     = (const float*)d_in[3];
    const float* cv2     = (const float*)d_in[4];
    const float* W_f1    = (const float*)d_in[5];
    const float* b_f1    = (const float*)d_in[6];
    const float* W_f2    = (const float*)d_in[7];
    const float* b_f2    = (const float*)d_in[8];
    const float* W_geo   = (const float*)d_in[9];
    const float* b_geo   = (const float*)d_in[10];
    const float* W_sel   = (const float*)d_in[11];
    const float* b_sel   = (const float*)d_in[12];

    float* finalO = (float*)d_out;
    float* icO    = (float*)d_out + 6422528;    // 4*49*128*256
    float* wO     = (float*)d_out + 12845056;   // + another 6422528

    unsigned int* Wb = (unsigned int*)d_ws;     // 16384 uints = 64 KB
    float* Mbuf  = (float*)((char*)d_ws + 65536);
    float* c0buf = Mbuf + 441;

    k_pre<<<65, 256, 0, stream>>>(W_f1, W_f2, Wb, W_sel, b_sel, W_geo, b_geo, Mbuf, c0buf);
    k_fused<<<512, 256, 0, stream>>>(feat_l1, feat_r1, Wb, b_f1, b_f2,
                                     cv0, cv1, cv2, Mbuf, c0buf,
                                     icO, finalO, wO);
}

// Round 12
// 274.127 us; speedup vs baseline: 1.0438x; 1.0438x over previous
//
#include <hip/hip_runtime.h>

#define HW 32768      // H*W per batch = 128*256
#define WIDTH 256

typedef float f32x4 __attribute__((ext_vector_type(4)));
typedef short s16x8 __attribute__((ext_vector_type(8)));

__device__ __forceinline__ unsigned short f2bf(float f){
    unsigned int u = __float_as_uint(f);
    u += 0x7FFFu + ((u >> 16) & 1u);      // round-to-nearest-even
    return (unsigned short)(u >> 16);
}
__device__ __forceinline__ unsigned int pk2(float a, float b){
    return (unsigned int)f2bf(a) | ((unsigned int)f2bf(b) << 16);
}

// ---------------------------------------------------------------------------
// k_pre: blocks 0..63 = W1/W2 pre-pack into bf16 MFMA A-fragment layout
//        block 64 = collapsed geo path (M = Wsel x Wgeo, c0 = collapsed bias)
// NOTE: Wb/M/c0 stores stay CACHED (k_fused re-reads them) — no nt here.
// ---------------------------------------------------------------------------
__global__ void k_pre(const float* __restrict__ W1, const float* __restrict__ W2,
                      unsigned int* __restrict__ Wb,
                      const float* __restrict__ Wsel, const float* __restrict__ bsel,
                      const float* __restrict__ Wgeo, const float* __restrict__ bgeo,
                      float* __restrict__ M, float* __restrict__ c0)
{
    if (blockIdx.x < 64){
        const int pi = blockIdx.x * 256 + threadIdx.x;   // 0..16383
        const int j2   = pi & 3;
        const int l15  = (pi >> 2) & 15;
        const int quad = (pi >> 6) & 3;
        const int m    = (pi >> 8) & 7;
        const int kk   = (pi >> 11) & 3;
        const int F    = (pi >> 13) & 1;
        const float* Wm = F ? W2 : W1;
        const int row = m * 16 + l15;
        const int ch  = kk * 32 + quad * 8 + j2 * 2;
        Wb[pi] = pk2(Wm[row * 128 + ch], Wm[row * 128 + ch + 1]);
    } else {
        for (int u = threadIdx.x; u < 444; u += 256){
            if (u < 441){
                int s = u / 147; int r = u % 147; int i = r / 49; int k = r % 49;
                float acc = 0.f;
                for (int o = 0; o < 96; ++o)
                    acc += Wsel[s * 288 + i * 96 + o] * Wgeo[o * 49 + k];
                M[u] = acc;
            } else {
                int s = u - 441;
                float acc = bsel[s];
                for (int i = 0; i < 3; ++i)
                    for (int o = 0; o < 96; ++o)
                        acc += Wsel[s * 288 + i * 96 + o] * bgeo[o];
                c0[s] = acc;
            }
        }
    }
}

// ---------------------------------------------------------------------------
// Fused kernel — EXACT round-1 structure (best measured: k_fused 112 us,
// total 274.9) with ONE change: all ic/final/w stores are NON-TEMPORAL.
// Mechanism: outputs (53 MB ideal) are write-once, never re-read in-kernel,
// yet measured WRITE_SIZE was 85-100 MB (~2x) — L2 RFO + dirty-eviction
// churn that also thrashes the cv pass-2 reads (294 KB/CU >> 128 KB/CU L2
// share). Streaming stores bypass that.
// ---------------------------------------------------------------------------
__global__ __launch_bounds__(256, 2) void k_fused(
    const float* __restrict__ fl, const float* __restrict__ fr,
    const unsigned int* __restrict__ Wbu,
    const float* __restrict__ b1, const float* __restrict__ b2,
    const float* __restrict__ cv0, const float* __restrict__ cv1,
    const float* __restrict__ cv2,
    const float* __restrict__ Mg, const float* __restrict__ c0g,
    float* __restrict__ icO, float* __restrict__ finalO, float* __restrict__ wO)
{
    __shared__ __align__(16) char pool[67584];      // f2s -> G (time-aliased)
    __shared__ float s1[256], s2[256];
    __shared__ float Ms[441];
    __shared__ float c0s[3];
    unsigned short* f2s = (unsigned short*)pool;    // [256 px][132] bf16
    float* G            = (float*)pool;             // [256 rows][66] f32

    const int blk  = blockIdx.x;          // 512 = 4 b x 128 h
    const int b    = blk >> 7;
    const int h    = blk & 127;
    const int tid  = threadIdx.x;
    const int wv   = tid >> 6;            // 0..3
    const int lane = tid & 63;
    const int quad = lane >> 4;
    const int l15  = lane & 15;

    for (int i = tid; i < 441; i += 256) Ms[i] = Mg[i];
    if (tid < 3) c0s[tid] = c0g[tid];

    const float* feats[2] = { fl + (size_t)b * 128 * HW + h * WIDTH,
                              fr + (size_t)b * 128 * HW + h * WIDTH };
    const float* bss[2]   = { b1, b2 };

    unsigned int f1p[64];                 // f1 raw bf16 pairs (wave's 64 px)

    #pragma unroll 1
    for (int Fi = 0; Fi < 2; ++Fi){
        const int F = 1 - Fi;             // f2 first, then f1
        const float* featB = feats[F];
        const float* bias  = bss[F];
        const unsigned int* WbF = Wbu + F * 8192;

        f32x4 acc[8][4];
        #pragma unroll
        for (int m = 0; m < 8; ++m)
            #pragma unroll
            for (int nt = 0; nt < 4; ++nt)
                acc[m][nt] = (f32x4){0.f, 0.f, 0.f, 0.f};

        float buf[3][8];
        // preload tiles 0,1  (tile t = kk*4+nt; px = wv*64 + nt*16 + l15)
        #pragma unroll
        for (int t = 0; t < 2; ++t){
            const float* bp = featB + (size_t)(quad * 8) * HW + wv * 64 + t * 16 + l15;
            #pragma unroll
            for (int j = 0; j < 8; ++j) buf[t][j] = bp[(size_t)j * HW];
        }

        #pragma unroll
        for (int kk = 0; kk < 4; ++kk){
            // A-frags: one 16-B coalesced load per m (pre-packed bf16, L2-hot)
            s16x8 af[8];
            #pragma unroll
            for (int m = 0; m < 8; ++m)
                af[m] = *(const s16x8*)&WbF[(((kk * 8 + m) * 4 + quad) * 16 + l15) * 4];

            #pragma unroll
            for (int nt = 0; nt < 4; ++nt){
                const int t = kk * 4 + nt;
                if (t + 2 < 16){          // 2-deep pipeline
                    const int kk2 = (t + 2) >> 2, nt2 = (t + 2) & 3;
                    const float* bp = featB + (size_t)(kk2 * 32 + quad * 8) * HW
                                      + wv * 64 + nt2 * 16 + l15;
                    #pragma unroll
                    for (int j = 0; j < 8; ++j) buf[(t + 2) % 3][j] = bp[(size_t)j * HW];
                }
                const float* cur = buf[t % 3];
                union { unsigned int u[4]; s16x8 v; } rb;
                rb.u[0] = pk2(cur[0], cur[1]); rb.u[1] = pk2(cur[2], cur[3]);
                rb.u[2] = pk2(cur[4], cur[5]); rb.u[3] = pk2(cur[6], cur[7]);
                #pragma unroll
                for (int m = 0; m < 8; ++m)
                    acc[m][nt] = __builtin_amdgcn_mfma_f32_16x16x32_bf16(af[m], rb.v, acc[m][nt], 0, 0, 0);
            }
        }

        // bias + inverse-norm per pixel
        float inv[4];
        #pragma unroll
        for (int nt = 0; nt < 4; ++nt){
            #pragma unroll
            for (int m = 0; m < 8; ++m)
                acc[m][nt] += *(const f32x4*)(bias + m * 16 + quad * 4);
            float n2 = 0.f;
            #pragma unroll
            for (int m = 0; m < 8; ++m)
                #pragma unroll
                for (int r = 0; r < 4; ++r)
                    n2 += acc[m][nt][r] * acc[m][nt][r];
            n2 += __shfl_xor(n2, 16, 64);
            n2 += __shfl_xor(n2, 32, 64);
            inv[nt] = 1.f / (sqrtf(n2) + 1e-8f);
        }

        if (F == 1){                      // f2 -> LDS (raw bf16) + s2
            if (quad == 0){
                #pragma unroll
                for (int nt = 0; nt < 4; ++nt) s2[wv * 64 + nt * 16 + l15] = inv[nt];
            }
            #pragma unroll
            for (int nt = 0; nt < 4; ++nt){
                const int px = wv * 64 + nt * 16 + l15;
                #pragma unroll
                for (int m = 0; m < 8; ++m){
                    uint2 p;
                    p.x = pk2(acc[m][nt][0], acc[m][nt][1]);
                    p.y = pk2(acc[m][nt][2], acc[m][nt][3]);
                    *(uint2*)&f2s[px * 132 + m * 16 + quad * 4] = p;
                }
            }
        } else {                          // f1 -> registers (raw bf16) + s1
            #pragma unroll
            for (int m = 0; m < 8; ++m)
                #pragma unroll
                for (int nt = 0; nt < 4; ++nt){
                    f1p[m * 8 + nt * 2 + 0] = pk2(acc[m][nt][0], acc[m][nt][1]);
                    f1p[m * 8 + nt * 2 + 1] = pk2(acc[m][nt][2], acc[m][nt][3]);
                }
            if (quad == 0){
                #pragma unroll
                for (int nt = 0; nt < 4; ++nt) s1[wv * 64 + nt * 16 + l15] = inv[nt];
            }
        }
    }
    __syncthreads();                      // f2s complete

    // ---- correlation: per wave 4 strips of 16 px; A from f1p shuffles ----
    f32x4 acc_c[4][4];
    #pragma unroll
    for (int st = 0; st < 4; ++st)
        #pragma unroll
        for (int ct = 0; ct < 4; ++ct)
            acc_c[st][ct] = (f32x4){0.f, 0.f, 0.f, 0.f};

    #pragma unroll
    for (int st = 0; st < 4; ++st){
        s16x8 afc[4];
        #pragma unroll
        for (int kk = 0; kk < 4; ++kk){
            union { unsigned int u[4]; s16x8 v; } r;
            #pragma unroll
            for (int j2 = 0; j2 < 4; ++j2){
                const int rp  = j2 & 1;
                const int qs  = (quad & 1) * 2 + (j2 >> 1);
                const int src = qs * 16 + l15;
                unsigned int a0 = (unsigned int)__shfl((int)f1p[(kk * 2 + 0) * 8 + st * 2 + rp], src, 64);
                unsigned int a1 = (unsigned int)__shfl((int)f1p[(kk * 2 + 1) * 8 + st * 2 + rp], src, 64);
                r.u[j2] = (quad >> 1) ? a1 : a0;
            }
            afc[kk] = r.v;
        }
        #pragma unroll
        for (int ct = 0; ct < 4; ++ct){
            const int s = wv * 64 + st * 16 + ct * 16 + l15 - 24;
            const bool valid = (s >= 0) && (s < WIDTH);
            const int sc = valid ? s : 0;
            #pragma unroll
            for (int kk = 0; kk < 4; ++kk){
                union { uint2 q2[2]; s16x8 v; } rb;
                rb.q2[0] = *(const uint2*)&f2s[sc * 132 + kk * 32 + quad * 8];
                rb.q2[1] = *(const uint2*)&f2s[sc * 132 + kk * 32 + quad * 8 + 4];
                s16x8 bf = rb.v;
                if (!valid) bf = (s16x8){0,0,0,0,0,0,0,0};
                acc_c[st][ct] = __builtin_amdgcn_mfma_f32_16x16x32_bf16(afc[kk], bf, acc_c[st][ct], 0, 0, 0);
            }
        }
    }
    __syncthreads();                      // all f2s reads done; G overwrites pool
    #pragma unroll
    for (int st = 0; st < 4; ++st)
        #pragma unroll
        for (int ct = 0; ct < 4; ++ct)
            #pragma unroll
            for (int r = 0; r < 4; ++r)
                G[((wv * 4 + st) * 16 + quad * 4 + r) * 66 + ct * 16 + l15] = acc_c[st][ct][r];
    __syncthreads();

    // ---- fused epilogue: thread = pixel; dd-loop with full-line writes ----
    // out[dd][px] = G[px][(px&15)+48-dd] * s1[px] * s2[px+24-dd]  (G=0 when OOB)
    const int px = tid;
    const float sc1 = s1[px];
    const float* Gp = &G[px * 66 + (px & 15) + 48];
    const size_t rowoff = (size_t)h * WIDTH + px;
    const size_t cvbase = (size_t)b * 49 * HW + rowoff;
    float* icb = icO    + cvbase;
    float* fnb = finalO + cvbase;
    const float* c0p = cv0 + cvbase;
    const float* c1p = cv1 + cvbase;
    const float* c2p = cv2 + cvbase;

    float lg0 = c0s[0], lg1 = c0s[1], lg2 = c0s[2];
    #pragma unroll 7
    for (int dd = 0; dd < 49; ++dd){
        int s2i = px + 24 - dd;
        s2i = s2i < 0 ? 0 : (s2i > 255 ? 255 : s2i);   // OOB -> G row is 0 anyway
        const float icv = Gp[-dd] * sc1 * s2[s2i];
        __builtin_nontemporal_store(icv, icb + (size_t)dd * HW);
        const float a0 = c0p[(size_t)dd * HW];
        const float a1 = c1p[(size_t)dd * HW];
        const float a2 = c2p[(size_t)dd * HW];
        lg0 += Ms[dd]       * a0 + Ms[49  + dd] * a1 + Ms[98  + dd] * a2;
        lg1 += Ms[147 + dd] * a0 + Ms[196 + dd] * a1 + Ms[245 + dd] * a2;
        lg2 += Ms[294 + dd] * a0 + Ms[343 + dd] * a1 + Ms[392 + dd] * a2;
    }

    const float mx = fmaxf(lg0, fmaxf(lg1, lg2));
    const float e0 = expf(lg0 - mx), e1 = expf(lg1 - mx), e2 = expf(lg2 - mx);
    const float inv = 1.f / (e0 + e1 + e2);
    const float w0 = e0 * inv, w1 = e1 * inv, w2 = e2 * inv;

    float* wb = wO + (size_t)b * 3 * HW + rowoff;
    __builtin_nontemporal_store(w0, wb);
    __builtin_nontemporal_store(w1, wb + HW);
    __builtin_nontemporal_store(w2, wb + 2 * HW);

    #pragma unroll 7
    for (int dd = 0; dd < 49; ++dd){
        int s2i = px + 24 - dd;
        s2i = s2i < 0 ? 0 : (s2i > 255 ? 255 : s2i);
        const float icv = Gp[-dd] * sc1 * s2[s2i];
        const float fv = icv + w0 * c0p[(size_t)dd * HW]
                             + w1 * c1p[(size_t)dd * HW]
                             + w2 * c2p[(size_t)dd * HW];
        __builtin_nontemporal_store(fv, fnb + (size_t)dd * HW);
    }
}

// ---------------------------------------------------------------------------
extern "C" void kernel_launch(void* const* d_in, const int* in_sizes, int n_in,
                              void* d_out, int out_size, void* d_ws, size_t ws_size,
                              hipStream_t stream)
{
    const float* feat_l1 = (const float*)d_in[0];
    const float* feat_r1 = (const float*)d_in[1];
    const float* cv0     = (const float*)d_in[2];
    const float* cv1     = (const float*)d_in[3];
    const float* cv2     = (const float*)d_in[4];
    const float* W_f1    = (const float*)d_in[5];
    const float* b_f1    = (const float*)d_in[6];
    const float* W_f2    = (const float*)d_in[7];
    const float* b_f2    = (const float*)d_in[8];
    const float* W_geo   = (const float*)d_in[9];
    const float* b_geo   = (const float*)d_in[10];
    const float* W_sel   = (const float*)d_in[11];
    const float* b_sel   = (const float*)d_in[12];

    float* finalO = (float*)d_out;
    float* icO    = (float*)d_out + 6422528;    // 4*49*128*256
    float* wO     = (float*)d_out + 12845056;   // + another 6422528

    unsigned int* Wb = (unsigned int*)d_ws;     // 16384 uints = 64 KB
    float* Mbuf  = (float*)((char*)d_ws + 65536);
    float* c0buf = Mbuf + 441;

    k_pre<<<65, 256, 0, stream>>>(W_f1, W_f2, Wb, W_sel, b_sel, W_geo, b_geo, Mbuf, c0buf);
    k_fused<<<512, 256, 0, stream>>>(feat_l1, feat_r1, Wb, b_f1, b_f2,
                                     cv0, cv1, cv2, Mbuf, c0buf,
                                     icO, finalO, wO);
}

// Round 15
// 269.175 us; speedup vs baseline: 1.0630x; 1.0184x over previous
//
#include <hip/hip_runtime.h>

#define HW 32768      // H*W per batch = 128*256
#define WIDTH 256

typedef float f32x4 __attribute__((ext_vector_type(4)));
typedef short s16x8 __attribute__((ext_vector_type(8)));

__device__ __forceinline__ unsigned short f2bf(float f){
    unsigned int u = __float_as_uint(f);
    u += 0x7FFFu + ((u >> 16) & 1u);      // round-to-nearest-even
    return (unsigned short)(u >> 16);
}
__device__ __forceinline__ unsigned int pk2(float a, float b){
    return (unsigned int)f2bf(a) | ((unsigned int)f2bf(b) << 16);
}

__device__ __forceinline__ void gload_lds16(const float* gsrc, float* ldst){
    __builtin_amdgcn_global_load_lds(
        (const __attribute__((address_space(1))) unsigned int*)gsrc,
        (__attribute__((address_space(3))) unsigned int*)ldst, 16, 0, 0);
}

// ---------------------------------------------------------------------------
// k_pre: blocks 0..63 = W1/W2 pre-pack into bf16 MFMA A-fragment layout
//        block 64 = collapsed geo path (M = Wsel x Wgeo, c0 = collapsed bias)
// ---------------------------------------------------------------------------
__global__ void k_pre(const float* __restrict__ W1, const float* __restrict__ W2,
                      unsigned int* __restrict__ Wb,
                      const float* __restrict__ Wsel, const float* __restrict__ bsel,
                      const float* __restrict__ Wgeo, const float* __restrict__ bgeo,
                      float* __restrict__ M, float* __restrict__ c0)
{
    if (blockIdx.x < 64){
        const int pi = blockIdx.x * 256 + threadIdx.x;   // 0..16383
        const int j2   = pi & 3;
        const int l15  = (pi >> 2) & 15;
        const int quad = (pi >> 6) & 3;
        const int m    = (pi >> 8) & 7;
        const int kk   = (pi >> 11) & 3;
        const int F    = (pi >> 13) & 1;
        const float* Wm = F ? W2 : W1;
        const int row = m * 16 + l15;
        const int ch  = kk * 32 + quad * 8 + j2 * 2;
        Wb[pi] = pk2(Wm[row * 128 + ch], Wm[row * 128 + ch + 1]);
    } else {
        for (int u = threadIdx.x; u < 444; u += 256){
            if (u < 441){
                int s = u / 147; int r = u % 147; int i = r / 49; int k = r % 49;
                float acc = 0.f;
                for (int o = 0; o < 96; ++o)
                    acc += Wsel[s * 288 + i * 96 + o] * Wgeo[o * 49 + k];
                M[u] = acc;
            } else {
                int s = u - 441;
                float acc = bsel[s];
                for (int i = 0; i < 3; ++i)
                    for (int o = 0; o < 96; ++o)
                        acc += Wsel[s * 288 + i * 96 + o] * bgeo[o];
                c0[s] = acc;
            }
        }
    }
}

// ---------------------------------------------------------------------------
// Fused kernel — R12 base. This round: the f2 GEMM stages feat tiles into
// the (currently idle) pool via global_load_lds 16B, double-buffered
// [2][32][258] fp32 (66 KB <= 67.58 KB), next K-block prefetched under
// compute, drained at the per-kk barrier. Fragment reads are ds_read_b32
// with row stride 258 (quads 2-way bank alias = free). f1 GEMM stays on the
// legacy scalar pipeline (pool holds f2s by then; reordering would exceed
// the 128-VGPR cap: acc 128 + f1p 64).
// ---------------------------------------------------------------------------
__global__ __launch_bounds__(256, 2) void k_fused(
    const float* __restrict__ fl, const float* __restrict__ fr,
    const unsigned int* __restrict__ Wbu,
    const float* __restrict__ b1, const float* __restrict__ b2,
    const float* __restrict__ cv0, const float* __restrict__ cv1,
    const float* __restrict__ cv2,
    const float* __restrict__ Mg, const float* __restrict__ c0g,
    float* __restrict__ icO, float* __restrict__ finalO, float* __restrict__ wO)
{
    __shared__ __align__(16) char pool[67584];      // stage -> f2s -> G (time-aliased)
    __shared__ float s1[256], s2[256];
    __shared__ float Ms[441];
    __shared__ float c0s[3];
    float* stageL       = (float*)pool;             // [2][32][258] f32 (f2 GEMM only)
    unsigned short* f2s = (unsigned short*)pool;    // [256 px][132] bf16
    float* G            = (float*)pool;             // [256 rows][66] f32

    const int blk  = blockIdx.x;          // 512 = 4 b x 128 h
    const int b    = blk >> 7;
    const int h    = blk & 127;
    const int tid  = threadIdx.x;
    const int wv   = tid >> 6;            // 0..3
    const int lane = tid & 63;
    const int quad = lane >> 4;
    const int l15  = lane & 15;

    for (int i = tid; i < 441; i += 256) Ms[i] = Mg[i];
    if (tid < 3) c0s[tid] = c0g[tid];

    unsigned int f1p[64];                 // f1 raw bf16 pairs (wave's 64 px)

    // ======================= Section A: f2 GEMM (staged) ====================
    {
        const float* featB = fr + (size_t)b * 128 * HW + h * WIDTH;
        const unsigned int* WbF = Wbu + 8192;      // F=1 weights

        f32x4 acc[8][4];
        #pragma unroll
        for (int m = 0; m < 8; ++m)
            #pragma unroll
            for (int nt = 0; nt < 4; ++nt)
                acc[m][nt] = (f32x4){0.f, 0.f, 0.f, 0.f};

        // prologue: stage kk=0 into half 0 (wave wv: rows wv*8..wv*8+7)
        #pragma unroll
        for (int r = 0; r < 8; ++r){
            const float* src = featB + (size_t)(wv * 8 + r) * HW;
            float* dst = stageL + (wv * 8 + r) * 258;
            gload_lds16(src + lane * 4, dst);
        }
        __syncthreads();

        #pragma unroll
        for (int kk = 0; kk < 4; ++kk){
            const int bsel = kk & 1;
            if (kk < 3){                   // prefetch next K-block into other half
                const int nb = (kk + 1) & 1;
                #pragma unroll
                for (int r = 0; r < 8; ++r){
                    const float* src = featB + (size_t)((kk + 1) * 32 + wv * 8 + r) * HW;
                    float* dst = stageL + nb * 8256 + (wv * 8 + r) * 258;
                    gload_lds16(src + lane * 4, dst);
                }
            }
            // A-frags: one 16-B coalesced load per m (pre-packed bf16, L2-hot)
            s16x8 af[8];
            #pragma unroll
            for (int m = 0; m < 8; ++m)
                af[m] = *(const s16x8*)&WbF[(((kk * 8 + m) * 4 + quad) * 16 + l15) * 4];

            const float* sb = stageL + bsel * 8256 + (quad * 8) * 258;
            #pragma unroll
            for (int nt = 0; nt < 4; ++nt){
                const int px = wv * 64 + nt * 16 + l15;
                union { unsigned int u[4]; s16x8 v; } rb;
                rb.u[0] = pk2(sb[0 * 258 + px], sb[1 * 258 + px]);
                rb.u[1] = pk2(sb[2 * 258 + px], sb[3 * 258 + px]);
                rb.u[2] = pk2(sb[4 * 258 + px], sb[5 * 258 + px]);
                rb.u[3] = pk2(sb[6 * 258 + px], sb[7 * 258 + px]);
                #pragma unroll
                for (int m = 0; m < 8; ++m)
                    acc[m][nt] = __builtin_amdgcn_mfma_f32_16x16x32_bf16(af[m], rb.v, acc[m][nt], 0, 0, 0);
            }
            __syncthreads();               // drains prefetch + guards dbuf reuse
        }

        // bias + inverse-norm per pixel
        float inv[4];
        #pragma unroll
        for (int nt = 0; nt < 4; ++nt){
            #pragma unroll
            for (int m = 0; m < 8; ++m)
                acc[m][nt] += *(const f32x4*)(b2 + m * 16 + quad * 4);
            float n2 = 0.f;
            #pragma unroll
            for (int m = 0; m < 8; ++m)
                #pragma unroll
                for (int r = 0; r < 4; ++r)
                    n2 += acc[m][nt][r] * acc[m][nt][r];
            n2 += __shfl_xor(n2, 16, 64);
            n2 += __shfl_xor(n2, 32, 64);
            inv[nt] = 1.f / (sqrtf(n2) + 1e-8f);
        }

        if (quad == 0){
            #pragma unroll
            for (int nt = 0; nt < 4; ++nt) s2[wv * 64 + nt * 16 + l15] = inv[nt];
        }
        // f2 -> LDS (raw bf16); overwrites the staging area (safe: barrier above)
        #pragma unroll
        for (int nt = 0; nt < 4; ++nt){
            const int px = wv * 64 + nt * 16 + l15;
            #pragma unroll
            for (int m = 0; m < 8; ++m){
                uint2 p;
                p.x = pk2(acc[m][nt][0], acc[m][nt][1]);
                p.y = pk2(acc[m][nt][2], acc[m][nt][3]);
                *(uint2*)&f2s[px * 132 + m * 16 + quad * 4] = p;
            }
        }
    }

    // ================= Section B: f1 GEMM (legacy scalar pipeline) ==========
    {
        const float* featB = fl + (size_t)b * 128 * HW + h * WIDTH;
        const unsigned int* WbF = Wbu;             // F=0 weights

        f32x4 acc[8][4];
        #pragma unroll
        for (int m = 0; m < 8; ++m)
            #pragma unroll
            for (int nt = 0; nt < 4; ++nt)
                acc[m][nt] = (f32x4){0.f, 0.f, 0.f, 0.f};

        float buf[3][8];
        #pragma unroll
        for (int t = 0; t < 2; ++t){
            const float* bp = featB + (size_t)(quad * 8) * HW + wv * 64 + t * 16 + l15;
            #pragma unroll
            for (int j = 0; j < 8; ++j) buf[t][j] = bp[(size_t)j * HW];
        }

        #pragma unroll
        for (int kk = 0; kk < 4; ++kk){
            s16x8 af[8];
            #pragma unroll
            for (int m = 0; m < 8; ++m)
                af[m] = *(const s16x8*)&WbF[(((kk * 8 + m) * 4 + quad) * 16 + l15) * 4];

            #pragma unroll
            for (int nt = 0; nt < 4; ++nt){
                const int t = kk * 4 + nt;
                if (t + 2 < 16){          // 2-deep pipeline
                    const int kk2 = (t + 2) >> 2, nt2 = (t + 2) & 3;
                    const float* bp = featB + (size_t)(kk2 * 32 + quad * 8) * HW
                                      + wv * 64 + nt2 * 16 + l15;
                    #pragma unroll
                    for (int j = 0; j < 8; ++j) buf[(t + 2) % 3][j] = bp[(size_t)j * HW];
                }
                const float* cur = buf[t % 3];
                union { unsigned int u[4]; s16x8 v; } rb;
                rb.u[0] = pk2(cur[0], cur[1]); rb.u[1] = pk2(cur[2], cur[3]);
                rb.u[2] = pk2(cur[4], cur[5]); rb.u[3] = pk2(cur[6], cur[7]);
                #pragma unroll
                for (int m = 0; m < 8; ++m)
                    acc[m][nt] = __builtin_amdgcn_mfma_f32_16x16x32_bf16(af[m], rb.v, acc[m][nt], 0, 0, 0);
            }
        }

        float inv[4];
        #pragma unroll
        for (int nt = 0; nt < 4; ++nt){
            #pragma unroll
            for (int m = 0; m < 8; ++m)
                acc[m][nt] += *(const f32x4*)(b1 + m * 16 + quad * 4);
            float n2 = 0.f;
            #pragma unroll
            for (int m = 0; m < 8; ++m)
                #pragma unroll
                for (int r = 0; r < 4; ++r)
                    n2 += acc[m][nt][r] * acc[m][nt][r];
            n2 += __shfl_xor(n2, 16, 64);
            n2 += __shfl_xor(n2, 32, 64);
            inv[nt] = 1.f / (sqrtf(n2) + 1e-8f);
        }

        #pragma unroll
        for (int m = 0; m < 8; ++m)
            #pragma unroll
            for (int nt = 0; nt < 4; ++nt){
                f1p[m * 8 + nt * 2 + 0] = pk2(acc[m][nt][0], acc[m][nt][1]);
                f1p[m * 8 + nt * 2 + 1] = pk2(acc[m][nt][2], acc[m][nt][3]);
            }
        if (quad == 0){
            #pragma unroll
            for (int nt = 0; nt < 4; ++nt) s1[wv * 64 + nt * 16 + l15] = inv[nt];
        }
    }
    __syncthreads();                      // f2s complete

    // ---- correlation: per wave 4 strips of 16 px; A from f1p shuffles ----
    f32x4 acc_c[4][4];
    #pragma unroll
    for (int st = 0; st < 4; ++st)
        #pragma unroll
        for (int ct = 0; ct < 4; ++ct)
            acc_c[st][ct] = (f32x4){0.f, 0.f, 0.f, 0.f};

    #pragma unroll
    for (int st = 0; st < 4; ++st){
        s16x8 afc[4];
        #pragma unroll
        for (int kk = 0; kk < 4; ++kk){
            union { unsigned int u[4]; s16x8 v; } r;
            #pragma unroll
            for (int j2 = 0; j2 < 4; ++j2){
                const int rp  = j2 & 1;
                const int qs  = (quad & 1) * 2 + (j2 >> 1);
                const int src = qs * 16 + l15;
                unsigned int a0 = (unsigned int)__shfl((int)f1p[(kk * 2 + 0) * 8 + st * 2 + rp], src, 64);
                unsigned int a1 = (unsigned int)__shfl((int)f1p[(kk * 2 + 1) * 8 + st * 2 + rp], src, 64);
                r.u[j2] = (quad >> 1) ? a1 : a0;
            }
            afc[kk] = r.v;
        }
        #pragma unroll
        for (int ct = 0; ct < 4; ++ct){
            const int s = wv * 64 + st * 16 + ct * 16 + l15 - 24;
            const bool valid = (s >= 0) && (s < WIDTH);
            const int sc = valid ? s : 0;
            #pragma unroll
            for (int kk = 0; kk < 4; ++kk){
                union { uint2 q2[2]; s16x8 v; } rb;
                rb.q2[0] = *(const uint2*)&f2s[sc * 132 + kk * 32 + quad * 8];
                rb.q2[1] = *(const uint2*)&f2s[sc * 132 + kk * 32 + quad * 8 + 4];
                s16x8 bf = rb.v;
                if (!valid) bf = (s16x8){0,0,0,0,0,0,0,0};
                acc_c[st][ct] = __builtin_amdgcn_mfma_f32_16x16x32_bf16(afc[kk], bf, acc_c[st][ct], 0, 0, 0);
            }
        }
    }
    __syncthreads();                      // all f2s reads done; G overwrites pool
    #pragma unroll
    for (int st = 0; st < 4; ++st)
        #pragma unroll
        for (int ct = 0; ct < 4; ++ct)
            #pragma unroll
            for (int r = 0; r < 4; ++r)
                G[((wv * 4 + st) * 16 + quad * 4 + r) * 66 + ct * 16 + l15] = acc_c[st][ct][r];
    __syncthreads();

    // ---- fused epilogue: thread = pixel; dd-loop with full-line writes ----
    const int px = tid;
    const float sc1 = s1[px];
    const float* Gp = &G[px * 66 + (px & 15) + 48];
    const size_t rowoff = (size_t)h * WIDTH + px;
    const size_t cvbase = (size_t)b * 49 * HW + rowoff;
    float* icb = icO    + cvbase;
    float* fnb = finalO + cvbase;
    const float* c0p = cv0 + cvbase;
    const float* c1p = cv1 + cvbase;
    const float* c2p = cv2 + cvbase;

    float lg0 = c0s[0], lg1 = c0s[1], lg2 = c0s[2];
    #pragma unroll 7
    for (int dd = 0; dd < 49; ++dd){
        int s2i = px + 24 - dd;
        s2i = s2i < 0 ? 0 : (s2i > 255 ? 255 : s2i);   // OOB -> G row is 0 anyway
        const float icv = Gp[-dd] * sc1 * s2[s2i];
        __builtin_nontemporal_store(icv, icb + (size_t)dd * HW);
        const float a0 = c0p[(size_t)dd * HW];
        const float a1 = c1p[(size_t)dd * HW];
        const float a2 = c2p[(size_t)dd * HW];
        lg0 += Ms[dd]       * a0 + Ms[49  + dd] * a1 + Ms[98  + dd] * a2;
        lg1 += Ms[147 + dd] * a0 + Ms[196 + dd] * a1 + Ms[245 + dd] * a2;
        lg2 += Ms[294 + dd] * a0 + Ms[343 + dd] * a1 + Ms[392 + dd] * a2;
    }

    const float mx = fmaxf(lg0, fmaxf(lg1, lg2));
    const float e0 = expf(lg0 - mx), e1 = expf(lg1 - mx), e2 = expf(lg2 - mx);
    const float inv = 1.f / (e0 + e1 + e2);
    const float w0 = e0 * inv, w1 = e1 * inv, w2 = e2 * inv;

    float* wb = wO + (size_t)b * 3 * HW + rowoff;
    __builtin_nontemporal_store(w0, wb);
    __builtin_nontemporal_store(w1, wb + HW);
    __builtin_nontemporal_store(w2, wb + 2 * HW);

    #pragma unroll 7
    for (int dd = 0; dd < 49; ++dd){
        int s2i = px + 24 - dd;
        s2i = s2i < 0 ? 0 : (s2i > 255 ? 255 : s2i);
        const float icv = Gp[-dd] * sc1 * s2[s2i];
        const float fv = icv + w0 * c0p[(size_t)dd * HW]
                             + w1 * c1p[(size_t)dd * HW]
                             + w2 * c2p[(size_t)dd * HW];
        __builtin_nontemporal_store(fv, fnb + (size_t)dd * HW);
    }
}

// ---------------------------------------------------------------------------
extern "C" void kernel_launch(void* const* d_in, const int* in_sizes, int n_in,
                              void* d_out, int out_size, void* d_ws, size_t ws_size,
                              hipStream_t stream)
{
    const float* feat_l1 = (const float*)d_in[0];
    const float* feat_r1 = (const float*)d_in[1];
    const float* cv0     = (const float*)d_in[2];
    const float* cv1     = (const float*)d_in[3];
    const float* cv2     = (const float*)d_in[4];
    const float* W_f1    = (const float*)d_in[5];
    const float* b_f1    = (const float*)d_in[6];
    const float* W_f2    = (const float*)d_in[7];
    const float* b_f2    = (const float*)d_in[8];
    const float* W_geo   = (const float*)d_in[9];
    const float* b_geo   = (const float*)d_in[10];
    const float* W_sel   = (const float*)d_in[11];
    const float* b_sel   = (const float*)d_in[12];

    float* finalO = (float*)d_out;
    float* icO    = (float*)d_out + 6422528;    // 4*49*128*256
    float* wO     = (float*)d_out + 12845056;   // + another 6422528

    unsigned int* Wb = (unsigned int*)d_ws;     // 16384 uints = 64 KB
    float* Mbuf  = (float*)((char*)d_ws + 65536);
    float* c0buf = Mbuf + 441;

    k_pre<<<65, 256, 0, stream>>>(W_f1, W_f2, Wb, W_sel, b_sel, W_geo, b_geo, Mbuf, c0buf);
    k_fused<<<512, 256, 0, stream>>>(feat_l1, feat_r1, Wb, b_f1, b_f2,
                                     cv0, cv1, cv2, Mbuf, c0buf,
                                     icO, finalO, wO);
}